// Round 7
// baseline (192.662 us; speedup 1.0000x reference)
//
#include <hip/hip_runtime.h>

#define NROWS 16384
#define KCODES 8192
#define DDIM 256

typedef _Float16 half8_t __attribute__((ext_vector_type(8)));
typedef float f32x4 __attribute__((ext_vector_type(4)));
typedef unsigned long long u64;
typedef unsigned int u32;

// ---------------- MFMA-path ws layout (byte offsets in d_ws) ----------------
// 0        : wht fp16[32][8192][8]  (4,194,304 B)  k-seg-major transposed w
// 4194304  : Z2  f32[16384]
// 4259840  : loss f32[1]
// 4260096  : part u32[8][16384][3]  (1,572,864 B)
#define WSO_Z2   4194304
#define WSO_LOSS 4259840
#define WSO_PART 4260096
#define WS_REQ   5832960
// zht fp16[32][16384][8] (8.4 MB) lives in d_out[0..16.8MB) quantized region;
// overwritten by vq_epi afterwards.

__device__ __forceinline__ u32 umin32(u32 a, u32 b) { return a < b ? a : b; }
__device__ __forceinline__ u32 umax32(u32 a, u32 b) { return a > b ? a : b; }
__device__ __forceinline__ u64 u64min(u64 a, u64 b) { return a < b ? a : b; }

__device__ __forceinline__ void load_lds16(const void* g, void* l) {
    __builtin_amdgcn_global_load_lds(
        (const __attribute__((address_space(1))) unsigned int*)g,
        (__attribute__((address_space(3))) unsigned int*)l, 16, 0, 0);
}

// ---------- fused prep: np-pairwise |z|^2 (float4) + transposed fp16 planes ----------
__global__ void vq_prep(const float* __restrict__ z, const float* __restrict__ cb,
                        float* __restrict__ z2, float* __restrict__ loss,
                        _Float16* __restrict__ zht, _Float16* __restrict__ wht) {
    const int tid = threadIdx.x;
    const int rl = tid & 15, s0 = tid >> 4;
    if (blockIdx.x < 1024) {
        const int rb = blockIdx.x * 16;
        // bitwise-np pairwise |z|^2, float4 form: 4 lanes/row = (half h, parity par).
        // element (par+2m)*4+j of half h lands in chain par*4+j, so an even/odd
        // float4 accumulator IS chains {r0..r3}/{r4..r7}; combine
        // ((r0+r1)+(r2+r3)) [+ shfl] ((r4+r5)+(r6+r7)), then lo+hi — np's tree.
        if (tid < 64) {
            const int row = rb + (tid >> 2);
            const int h = (tid >> 1) & 1, par = tid & 1;
            const float4* p = (const float4*)(z + (size_t)row * DDIM + h * 128);
            float4 c = {0.0f, 0.0f, 0.0f, 0.0f};
            #pragma unroll
            for (int m = 0; m < 16; m++) {
                const float4 v = p[par + 2 * m];
                c.x = __fadd_rn(c.x, __fmul_rn(v.x, v.x));
                c.y = __fadd_rn(c.y, __fmul_rn(v.y, v.y));
                c.z = __fadd_rn(c.z, __fmul_rn(v.z, v.z));
                c.w = __fadd_rn(c.w, __fmul_rn(v.w, v.w));
            }
            const float pr = __fadd_rn(__fadd_rn(c.x, c.y), __fadd_rn(c.z, c.w));
            const float sh = __fadd_rn(pr, __shfl_xor(pr, 1, 64));   // half-sum
            const float tot = __fadd_rn(sh, __shfl_xor(sh, 2, 64));  // lo+hi
            if ((tid & 3) == 0) z2[row] = tot;
        }
        if (blockIdx.x == 0 && tid == 0) loss[0] = 0.0f;
        // z -> fp16, k-seg-major transposed: zht[s][row][8]
        #pragma unroll
        for (int it = 0; it < 2; it++) {
            const int s = s0 + it * 16;
            const float4* zp = (const float4*)(z + (size_t)(rb + rl) * DDIM + s * 8);
            const float4 a = zp[0], b = zp[1];
            const half8_t H = {(_Float16)a.x, (_Float16)a.y, (_Float16)a.z, (_Float16)a.w,
                               (_Float16)b.x, (_Float16)b.y, (_Float16)b.z, (_Float16)b.w};
            ((half8_t*)zht)[(size_t)s * NROWS + rb + rl] = H;
        }
    } else {
        const int wb = (blockIdx.x - 1024) * 16;
        // w*8192 -> fp16 (exact pow2 scale), transposed: wht[s][code][8]
        #pragma unroll
        for (int it = 0; it < 2; it++) {
            const int s = s0 + it * 16;
            const float4* wp = (const float4*)(cb + (size_t)(wb + rl) * DDIM + s * 8);
            const float4 a = wp[0], b = wp[1];
            const half8_t H = {(_Float16)(a.x * 8192.0f), (_Float16)(a.y * 8192.0f),
                               (_Float16)(a.z * 8192.0f), (_Float16)(a.w * 8192.0f),
                               (_Float16)(b.x * 8192.0f), (_Float16)(b.y * 8192.0f),
                               (_Float16)(b.z * 8192.0f), (_Float16)(b.w * 8192.0f)};
            ((half8_t*)wht)[(size_t)s * KCODES + wb + rl] = H;
        }
    }
}

// ---------- single-pass fp16 MFMA GEMM, 128x1024 block, BK=64 ----------
// (unchanged from round 6 — passing, spill-free, conflict-free)
__global__ __launch_bounds__(256, 2) void vq_gemm(
    const _Float16* __restrict__ zht, const _Float16* __restrict__ wht,
    const float* __restrict__ Z2, u32* __restrict__ part) {
    __shared__ __align__(16) _Float16 Ah[8192];    // [8 seg][128 row][8]
    __shared__ __align__(16) _Float16 Bh[16384];   // [8 seg][256 code][8]
    __shared__ float sC[128];                      // Z2*65536 per block row
    __shared__ u32 sR[2][128][3];
    const int tid = threadIdx.x;
    const int wv = tid >> 6, ln = tid & 63;
    const int lo16 = ln & 15, quad = ln >> 4;
    const int wm = wv >> 1, wn = wv & 1;
    const int n0 = blockIdx.x * 128;
    const unsigned jb = blockIdx.y * 1024;

    if (tid < 128) sC[tid] = Z2[n0 + tid] * 65536.0f;   // exact: mult by 2^16

    u32 b1[16], b2[16];
    #pragma unroll
    for (int s = 0; s < 16; s++) { b1[s] = 0xFFFFFFFFu; b2[s] = 0xFFFFFFFFu; }

    #pragma unroll 1
    for (int jt = 0; jt < 4; jt++) {
        const unsigned jtb = jb + jt * 256;
        f32x4 acc[4][8];
        #pragma unroll
        for (int mt = 0; mt < 4; mt++)
            #pragma unroll
            for (int nt = 0; nt < 8; nt++) acc[mt][nt] = (f32x4)0.0f;

        #pragma unroll 1
        for (int ks = 0; ks < 4; ks++) {
            const int ksg = ks * 8;
            __syncthreads();   // prior-stage frag reads complete (covers sC too)
            #pragma unroll
            for (int r = 0; r < 4; r++) {
                const int c = r * 256 + tid;
                const int s = c >> 7, row = c & 127;
                load_lds16(zht + ((size_t)(ksg + s) * NROWS + n0 + row) * 8,
                           &Ah[(size_t)(r * 256 + wv * 64) * 8]);
            }
            #pragma unroll
            for (int r = 0; r < 8; r++) {
                const int c = r * 256 + tid;
                const int s = c >> 8, code = c & 255;
                load_lds16(wht + ((size_t)(ksg + s) * KCODES + jtb + code) * 8,
                           &Bh[(size_t)(r * 256 + wv * 64) * 8]);
            }
            __syncthreads();   // barrier drains vmcnt -> tiles ready
            #pragma unroll
            for (int ksub = 0; ksub < 2; ksub++) {
                half8_t af[4];
                #pragma unroll
                for (int mt = 0; mt < 4; mt++)
                    af[mt] = *(const half8_t*)
                        &Ah[((ksub * 4 + quad) * 128 + wm * 64 + mt * 16 + lo16) * 8];
                #pragma unroll
                for (int nt = 0; nt < 8; nt++) {
                    const half8_t bf = *(const half8_t*)
                        &Bh[((ksub * 4 + quad) * 256 + wn * 128 + nt * 16 + lo16) * 8];
                    #pragma unroll
                    for (int mt = 0; mt < 4; mt++)
                        acc[mt][nt] = __builtin_amdgcn_mfma_f32_16x16x32_f16(
                            af[mt], bf, acc[mt][nt], 0, 0, 0);
                }
            }
        }
        // per-jt epilogue: key + per-thread top-2 insert (3 min/max)
        const unsigned colb = jtb + wn * 128 + lo16;
        #pragma unroll
        for (int mt = 0; mt < 4; mt++) {
            #pragma unroll
            for (int rg = 0; rg < 4; rg++) {
                const int s = mt * 4 + rg;
                const int rl = wm * 64 + mt * 16 + quad * 4 + rg;
                const float C = sC[rl];
                const u32 Dc = (((u32)(262144 - (int)C)) << 13) + colb;
                #pragma unroll
                for (int nt = 0; nt < 8; nt++) {
                    const float f = fmaf(acc[mt][nt][rg], -16.0f, C);
                    const u32 key = (((u32)(int)f) << 13) + (Dc + nt * 16);
                    const u32 mx = umax32(key, b1[s]);
                    b1[s] = umin32(key, b1[s]);
                    b2[s] = umin32(mx, b2[s]);
                }
            }
        }
    }

    // 16-lane merge (top-2 pairs -> top-3), then cross-wn, write part
    #pragma unroll
    for (int s = 0; s < 16; s++) {
        u32 x1 = b1[s], x2 = b2[s], x3 = 0xFFFFFFFFu;
        #pragma unroll
        for (int m = 1; m < 16; m <<= 1) {
            const u32 o1 = __shfl_xor(x1, m, 64);
            const u32 o2 = __shfl_xor(x2, m, 64);
            const u32 o3 = __shfl_xor(x3, m, 64);
            const u32 hi1 = umax32(x1, o1), lo2 = umin32(x2, o2);
            const u32 hi2 = umax32(x2, o2), lo3 = umin32(x3, o3);
            const u32 n1 = umin32(x1, o1);
            const u32 n2 = umin32(hi1, lo2);
            const u32 n3 = umin32(umax32(hi1, lo2), umin32(hi2, lo3));
            x1 = n1; x2 = n2; x3 = n3;
        }
        if (lo16 == 0) {
            const int rl = wm * 64 + (s >> 2) * 16 + quad * 4 + (s & 3);
            sR[wn][rl][0] = x1; sR[wn][rl][1] = x2; sR[wn][rl][2] = x3;
        }
    }
    __syncthreads();
    if (tid < 128) {
        const u32 a1 = sR[0][tid][0], a2 = sR[0][tid][1], a3 = sR[0][tid][2];
        const u32 o1 = sR[1][tid][0], o2 = sR[1][tid][1], o3 = sR[1][tid][2];
        const u32 hi1 = umax32(a1, o1), lo2 = umin32(a2, o2);
        const u32 hi2 = umax32(a2, o2), lo3 = umin32(a3, o3);
        const u32 n1 = umin32(a1, o1);
        const u32 n2 = umin32(hi1, lo2);
        const u32 n3 = umin32(umax32(hi1, lo2), umin32(hi2, lo3));
        const size_t pb = ((size_t)blockIdx.y * NROWS + n0 + tid) * 3;
        part[pb] = n1; part[pb + 1] = n2; part[pb + 2] = n3;
    }
}

// ---------- fused epilogue: merge + quarter-split rescore + gather/ST + loss ----------
__global__ void vq_epi(const float* __restrict__ z, const float* __restrict__ cb,
                       const float* __restrict__ Z2, const u32* __restrict__ part,
                       float* __restrict__ out, float* __restrict__ loss) {
    __shared__ int scand[64][3];
    __shared__ int sfin[64];
    __shared__ float red[256];
    const int t = threadIdx.x;
    const int rb = blockIdx.x * 64;
    if (t < 64) {
        const int row = rb + t;
        u32 x1 = 0xFFFFFFFFu, x2 = 0xFFFFFFFFu, x3 = 0xFFFFFFFFu;
        #pragma unroll
        for (int g = 0; g < 8; g++) {
            const size_t p = ((size_t)g * NROWS + row) * 3;
            const u32 o1 = part[p], o2 = part[p + 1], o3 = part[p + 2];
            const u32 hi1 = umax32(x1, o1), lo2 = umin32(x2, o2);
            const u32 hi2 = umax32(x2, o2), lo3 = umin32(x3, o3);
            const u32 n1 = umin32(x1, o1);
            const u32 n2 = umin32(hi1, lo2);
            const u32 n3 = umin32(umax32(hi1, lo2), umin32(hi2, lo3));
            x1 = n1; x2 = n2; x3 = n3;
        }
        scand[t][0] = (int)(x1 & 8191u);
        scand[t][1] = (int)(x2 & 8191u);
        scand[t][2] = (int)(x3 & 8191u);
    }
    __syncthreads();
    {
        // rescore: 4 lanes per row = 4 d-quarters; z quarter read ONCE into
        // registers, 3 candidate dots accumulated per-quarter then combined
        // (p0+p1)+(p2+p3) via quad shuffles. Dot error ~1e-9 << 7.6e-6 grid
        // ulp -> same exactness class as rounds 2-6 (absmax 0).
        const int row = rb + (t >> 2), dq = t & 3;
        const float4* zq = (const float4*)(z + (size_t)row * DDIM + dq * 64);
        float4 zv[16];
        #pragma unroll
        for (int m = 0; m < 16; m++) zv[m] = zq[m];
        float pc[3];
        #pragma unroll
        for (int c = 0; c < 3; c++) {
            const int idx = scand[t >> 2][c];
            const float4* wq = (const float4*)(cb + (size_t)idx * DDIM + dq * 64);
            float a = 0.0f;
            #pragma unroll
            for (int m = 0; m < 16; m++) {
                const float4 w4 = wq[m];
                a = fmaf(zv[m].x, w4.x, a); a = fmaf(zv[m].y, w4.y, a);
                a = fmaf(zv[m].z, w4.z, a); a = fmaf(zv[m].w, w4.w, a);
            }
            pc[c] = a;
        }
        const float z2r = Z2[row];
        u64 best = 0xFFFFFFFFFFFFFFFFull;
        #pragma unroll
        for (int c = 0; c < 3; c++) {
            float s = pc[c] + __shfl_xor(pc[c], 1, 64);
            s = s + __shfl_xor(s, 2, 64);
            const float sc = fmaf(s, -2.0f, z2r);   // single-rounded np grid
            const u64 key = ((u64)__float_as_uint(sc) << 32) | (unsigned)scand[t >> 2][c];
            best = u64min(best, key);
        }
        if (dq == 0) {
            const int fi = (int)(best & 0xffffffffULL);
            sfin[t >> 2] = fi;
            out[4194305 + row] = (float)fi;
        }
    }
    __syncthreads();
    const float4* z4 = (const float4*)z;
    const float4* cb4 = (const float4*)cb;
    float4* o4 = (float4*)out;
    float lsum = 0.0f;
    #pragma unroll 4
    for (int k0 = 0; k0 < 16; k0++) {
        const int k = k0 * 256 + t;
        const int rl = k >> 6;
        const int cc = k & 63;
        const int row = rb + rl;
        const int idx = sfin[rl];
        const float4 zz = z4[(size_t)row * 64 + cc];
        const float4 qq = cb4[(size_t)idx * 64 + cc];
        float4 st;
        st.x = zz.x + (qq.x - zz.x);   // straight-through, fp32 order preserved
        st.y = zz.y + (qq.y - zz.y);
        st.z = zz.z + (qq.z - zz.z);
        st.w = zz.w + (qq.w - zz.w);
        o4[(size_t)row * 64 + cc] = st;
        const float dx = zz.x - qq.x, dy = zz.y - qq.y;
        const float dz = zz.z - qq.z, dw = zz.w - qq.w;
        lsum += dx * dx + dy * dy + dz * dz + dw * dw;
    }
    red[t] = lsum;
    __syncthreads();
    for (int s = 128; s > 0; s >>= 1) {
        if (t < s) red[t] += red[t + s];
        __syncthreads();
    }
    if (t == 0) atomicAdd(loss, red[0]);
}

__global__ void vq_phase3(const float* __restrict__ loss, float* __restrict__ out) {
    if (threadIdx.x == 0)
        out[4194304] = 1.25f * (loss[0] * (1.0f / 4194304.0f));
}

// ================= fallback (round-2 verbatim VALU path) =================
#define KSPLIT 8
#define CPB (KCODES / KSPLIT)
#define MT 128
#define JT 128
#define DT 32

__global__ void vq_z2_fb(const float* __restrict__ z, float* __restrict__ z2,
                         float* __restrict__ loss) {
    const int row = blockIdx.x * 256 + threadIdx.x;
    const float4* z4 = (const float4*)(z + (size_t)row * DDIM);
    float r[2][8];
    #pragma unroll
    for (int h = 0; h < 2; h++)
        #pragma unroll
        for (int k = 0; k < 8; k++) r[h][k] = 0.0f;
    #pragma unroll
    for (int m = 0; m < 64; m++) {
        const float4 v = z4[m];
        const int h = m >> 5;
        const int b = (m & 31) * 4;
        r[h][(b + 0) & 7] = __fadd_rn(r[h][(b + 0) & 7], __fmul_rn(v.x, v.x));
        r[h][(b + 1) & 7] = __fadd_rn(r[h][(b + 1) & 7], __fmul_rn(v.y, v.y));
        r[h][(b + 2) & 7] = __fadd_rn(r[h][(b + 2) & 7], __fmul_rn(v.z, v.z));
        r[h][(b + 3) & 7] = __fadd_rn(r[h][(b + 3) & 7], __fmul_rn(v.w, v.w));
    }
    float s[2];
    #pragma unroll
    for (int h = 0; h < 2; h++) {
        const float t01 = __fadd_rn(r[h][0], r[h][1]);
        const float t23 = __fadd_rn(r[h][2], r[h][3]);
        const float t45 = __fadd_rn(r[h][4], r[h][5]);
        const float t67 = __fadd_rn(r[h][6], r[h][7]);
        s[h] = __fadd_rn(__fadd_rn(t01, t23), __fadd_rn(t45, t67));
    }
    z2[row] = __fadd_rn(s[0], s[1]);
    if (blockIdx.x == 0 && threadIdx.x == 0) loss[0] = 0.0f;
}

__global__ __launch_bounds__(256) void vq_phase1_fb(const float* __restrict__ z,
                                                    const float* __restrict__ cb,
                                                    const float* __restrict__ Z2,
                                                    float* __restrict__ pval,
                                                    int* __restrict__ pidx) {
    __shared__ float As[DT][MT];
    __shared__ float Bs[DT][JT];
    const int tid = threadIdx.x;
    const int tx = tid & 15;
    const int ty = tid >> 4;
    const int n0 = blockIdx.x * MT;
    const int jbase = blockIdx.y * CPB;
    float z2r[8];
    #pragma unroll
    for (int i = 0; i < 8; i++) {
        const int rl = (i < 4) ? (4 * ty + i) : (64 + 4 * ty + (i - 4));
        z2r[i] = Z2[n0 + rl];
    }
    float bestv[8];
    int besti[8];
    #pragma unroll
    for (int i = 0; i < 8; i++) { bestv[i] = 3.0e38f; besti[i] = 0x7fffffff; }
    for (int jt = 0; jt < CPB; jt += JT) {
        float acc[8][8];
        #pragma unroll
        for (int i = 0; i < 8; i++)
            #pragma unroll
            for (int j = 0; j < 8; j++) acc[i][j] = 0.0f;
        for (int dt = 0; dt < DDIM; dt += DT) {
            __syncthreads();
            #pragma unroll
            for (int p = 0; p < 4; p++) {
                const int g = tid + p * 256;
                const int row = g >> 3;
                const int seg = g & 7;
                const float4 va = *(const float4*)(z + (size_t)(n0 + row) * DDIM + dt + seg * 4);
                As[seg * 4 + 0][row] = va.x;
                As[seg * 4 + 1][row] = va.y;
                As[seg * 4 + 2][row] = va.z;
                As[seg * 4 + 3][row] = va.w;
                const float4 vb = *(const float4*)(cb + (size_t)(jbase + jt + row) * DDIM + dt + seg * 4);
                Bs[seg * 4 + 0][row] = vb.x;
                Bs[seg * 4 + 1][row] = vb.y;
                Bs[seg * 4 + 2][row] = vb.z;
                Bs[seg * 4 + 3][row] = vb.w;
            }
            __syncthreads();
            #pragma unroll 4
            for (int dd = 0; dd < DT; dd++) {
                float a[8], b[8];
                *(float4*)(a)     = *(const float4*)(&As[dd][4 * ty]);
                *(float4*)(a + 4) = *(const float4*)(&As[dd][64 + 4 * ty]);
                *(float4*)(b)     = *(const float4*)(&Bs[dd][4 * tx]);
                *(float4*)(b + 4) = *(const float4*)(&Bs[dd][64 + 4 * tx]);
                #pragma unroll
                for (int i = 0; i < 8; i++)
                    #pragma unroll
                    for (int j = 0; j < 8; j++)
                        acc[i][j] += a[i] * b[j];
            }
        }
        #pragma unroll
        for (int c = 0; c < 8; c++) {
            const int jl = (c < 4) ? (4 * tx + c) : (64 + 4 * tx + (c - 4));
            const int jg = jbase + jt + jl;
            #pragma unroll
            for (int i = 0; i < 8; i++) {
                const float sc = z2r[i] - 2.0f * acc[i][c];
                if (sc < bestv[i] || (sc == bestv[i] && jg < besti[i])) {
                    bestv[i] = sc;
                    besti[i] = jg;
                }
            }
        }
    }
    __syncthreads();
    float* lv = &As[0][0];
    int* li = (int*)&Bs[0][0];
    #pragma unroll
    for (int i = 0; i < 8; i++) {
        const int rl = (i < 4) ? (4 * ty + i) : (64 + 4 * ty + (i - 4));
        lv[rl * 16 + tx] = bestv[i];
        li[rl * 16 + tx] = besti[i];
    }
    __syncthreads();
    if (tid < MT) {
        float bv = lv[tid * 16];
        int bi = li[tid * 16];
        #pragma unroll
        for (int t = 1; t < 16; t++) {
            const float v = lv[tid * 16 + t];
            const int ix = li[tid * 16 + t];
            if (v < bv || (v == bv && ix < bi)) { bv = v; bi = ix; }
        }
        pval[blockIdx.y * NROWS + n0 + tid] = bv;
        pidx[blockIdx.y * NROWS + n0 + tid] = bi;
    }
}

__global__ void vq_phase2_fb(const float* __restrict__ z, const float* __restrict__ cb,
                             const float* __restrict__ pval, const int* __restrict__ pidx,
                             float* __restrict__ out, float* __restrict__ loss) {
    __shared__ int sidx[64];
    __shared__ float red[256];
    const int t = threadIdx.x;
    const int rowbase = blockIdx.x * 64;
    if (t < 64) {
        const int row = rowbase + t;
        float bv = pval[row];
        int bi = pidx[row];
        #pragma unroll
        for (int s = 1; s < KSPLIT; s++) {
            const float v = pval[s * NROWS + row];
            const int ix = pidx[s * NROWS + row];
            if (v < bv || (v == bv && ix < bi)) { bv = v; bi = ix; }
        }
        sidx[t] = bi;
        out[4194305 + row] = (float)bi;
    }
    __syncthreads();
    const float4* z4 = (const float4*)z;
    const float4* cb4 = (const float4*)cb;
    float4* o4 = (float4*)out;
    float lsum = 0.0f;
    #pragma unroll 4
    for (int k0 = 0; k0 < 16; k0++) {
        const int k = k0 * 256 + t;
        const int rl = k >> 6;
        const int c = k & 63;
        const int row = rowbase + rl;
        const int idx = sidx[rl];
        const float4 zz = z4[(size_t)row * 64 + c];
        const float4 qq = cb4[(size_t)idx * 64 + c];
        float4 st;
        st.x = zz.x + (qq.x - zz.x);
        st.y = zz.y + (qq.y - zz.y);
        st.z = zz.z + (qq.z - zz.z);
        st.w = zz.w + (qq.w - zz.w);
        o4[(size_t)row * 64 + c] = st;
        const float dx = zz.x - qq.x;
        const float dy = zz.y - qq.y;
        const float dz = zz.z - qq.z;
        const float dw = zz.w - qq.w;
        lsum += dx * dx + dy * dy + dz * dz + dw * dw;
    }
    red[t] = lsum;
    __syncthreads();
    for (int s = 128; s > 0; s >>= 1) {
        if (t < s) red[t] += red[t + s];
        __syncthreads();
    }
    if (t == 0) atomicAdd(loss, red[0]);
}

// =========================================================================
extern "C" void kernel_launch(void* const* d_in, const int* in_sizes, int n_in,
                              void* d_out, int out_size, void* d_ws, size_t ws_size,
                              hipStream_t stream) {
    const float* z = (const float*)d_in[0];
    const float* cb = (const float*)d_in[1];
    float* out = (float*)d_out;
    char* wsb = (char*)d_ws;

    if (ws_size >= (size_t)WS_REQ) {
        _Float16* wht = (_Float16*)wsb;
        float* Z2 = (float*)(wsb + WSO_Z2);
        float* loss = (float*)(wsb + WSO_LOSS);
        u32* part = (u32*)(wsb + WSO_PART);
        _Float16* zht = (_Float16*)d_out;   // scratch in quantized region

        vq_prep<<<1536, 256, 0, stream>>>(z, cb, Z2, loss, zht, wht);
        vq_gemm<<<dim3(NROWS / 128, 8), 256, 0, stream>>>(zht, wht, Z2, part);
        vq_epi<<<NROWS / 64, 256, 0, stream>>>(z, cb, Z2, part, out, loss);
        vq_phase3<<<1, 64, 0, stream>>>(loss, out);
    } else {
        float* ws = (float*)d_ws;
        float* Z2 = ws;
        float* loss = ws + 16384;
        float* pval = ws + 32768;
        int* pidx = (int*)(ws + 163840);
        vq_z2_fb<<<NROWS / 256, 256, 0, stream>>>(z, Z2, loss);
        vq_phase1_fb<<<dim3(NROWS / MT, KSPLIT), 256, 0, stream>>>(z, cb, Z2, pval, pidx);
        vq_phase2_fb<<<NROWS / 64, 256, 0, stream>>>(z, cb, pval, pidx, out, loss);
        vq_phase3<<<1, 64, 0, stream>>>(loss, out);
    }
}